// Round 2
// baseline (418.163 us; speedup 1.0000x reference)
//
#include <hip/hip_runtime.h>
#include <hip/hip_bf16.h>

// RWKV6 single-token self-attention, H=4096, NH=64, HS=64, TM=64, TD=128.
// R7: k4/k6 software-pipelined — long-lived waves, register double-buffer,
// in-flight loads never drain to 0 (prefetch next row before consuming
// current; sched_barrier after each issue pins the order, compiler emits
// partial vmcnt waits). 4 rows/wave in k4, 2 rows/wave in k6.
//
// Kernel chain (stream-ordered):
//  k1 : dtype-detect + LayerNorm(x) -> xl (output 1), sx, xxx
//  k2a: partial dots for z = tanh(xxx @ maa_w1)   (split-K over 64 blocks)
//  k2c: reduce+tanh z, LoRA up -> mvals[5][4096]
//  k3a: partial dots for dz = tanh(mw @ decay_w1) (split-K over 128 blocks)
//  k3b: reduce+tanh dz, td = exp(-exp(clip(dz @ decay_w2 + time_decay)))
//  k4 : 4 matvecs r,k,v,g (1024 blocks, 4 rows/wave pipelined), silu on g
//  k5 : per-head kv outer, wkv readout, state2 update (output 2),
//       instance-norm + affine + gate -> og
//  k6 : out0 = x + og @ Wo.T (output 0), 512 blocks, 2 rows/wave pipelined

#define HDIM 4096
#define NHEAD 64
#define HSZ 64

#define WS_XL    0
#define WS_SX    4096
#define WS_XXX   8192
#define WS_MV    12288           // 5*4096: f=0 mw, 1 mk, 2 mv, 3 mr, 4 mg
#define WS_PART  32768           // 64*320 = 20480
#define WS_DPART 32768           // overlay: 128*128 = 16384 (PART dead by k3a)
#define WS_TD    53248
#define WS_R     57344
#define WS_K     61440
#define WS_V     65536
#define WS_G     69632
#define WS_OG    73728
#define WS_FLAG  77824
// total 77825 floats ~= 311 KB of d_ws

typedef unsigned short bfraw;

__device__ __forceinline__ float bf2f(bfraw u) {
    union { unsigned int u; float f; } v; v.u = ((unsigned int)u) << 16; return v.f;
}
__device__ __forceinline__ bfraw f2bf(float f) {
    union { float f; unsigned int u; } v; v.f = f;
    unsigned int u = v.u;
    unsigned int r = (u + 0x7fffu + ((u >> 16) & 1u)) >> 16;  // RNE
    return (bfraw)r;
}
__device__ __forceinline__ float ldin(const void* p, long long i, bool isbf) {
    return isbf ? bf2f(((const bfraw*)p)[i]) : ((const float*)p)[i];
}
__device__ __forceinline__ void stout(void* p, long long i, float v, bool isbf) {
    if (isbf) ((bfraw*)p)[i] = f2bf(v); else ((float*)p)[i] = v;
}
__device__ __forceinline__ float waveReduce(float v) {
    for (int m = 32; m; m >>= 1) v += __shfl_xor(v, m);
    return v;
}

// ---------------- k1: dtype detect + layernorm + token-shift mix ---------
__global__ __launch_bounds__(256)
void k1_ln_mix(const void* __restrict__ x, const void* __restrict__ st1,
               const void* __restrict__ lnw, const void* __restrict__ lnb,
               const void* __restrict__ tmx, void* __restrict__ dout,
               float* __restrict__ ws) {
    int tid = threadIdx.x;
    __shared__ float red[8];
    __shared__ float sflag;
    {
        const bfraw* p = (const bfraw*)x;
        bfraw u = p[tid];
        int e = (u >> 7) & 0xFF;
        int cnt = (e >= 96 && e <= 144) ? 1 : 0;   // |v| in ~[2^-31, 2^17]
        for (int m = 32; m; m >>= 1) cnt += __shfl_xor(cnt, m);
        if ((tid & 63) == 0) red[tid >> 6] = (float)cnt;
        __syncthreads();
        if (tid == 0) {
            float c = red[0] + red[1] + red[2] + red[3];
            float fl = (c >= 208.0f) ? 1.0f : 0.0f;
            sflag = fl;
            ws[WS_FLAG] = fl;
        }
        __syncthreads();
    }
    bool isbf = sflag != 0.0f;

    float xv[16];
    float s1 = 0.f, s2 = 0.f;
    for (int k = 0; k < 16; ++k) {
        float v = ldin(x, tid + k * 256, isbf);
        xv[k] = v; s1 += v; s2 += v * v;
    }
    s1 = waveReduce(s1); s2 = waveReduce(s2);
    int wid = tid >> 6, lane = tid & 63;
    if (lane == 0) { red[wid] = s1; red[4 + wid] = s2; }
    __syncthreads();
    float t1 = red[0] + red[1] + red[2] + red[3];
    float t2 = red[4] + red[5] + red[6] + red[7];
    float mu = t1 * (1.0f / HDIM);
    float var = fmaxf(t2 * (1.0f / HDIM) - mu * mu, 0.0f);
    float rstd = rsqrtf(var + 1e-5f);
    for (int k = 0; k < 16; ++k) {
        int i = tid + k * 256;
        float xl = (xv[k] - mu) * rstd * ldin(lnw, i, isbf) + ldin(lnb, i, isbf);
        float sx = ldin(st1, i, isbf) - xl;
        float xxx = xl + sx * ldin(tmx, i, isbf);
        stout(dout, 4096 + i, xl, isbf);   // output 1: xl
        ws[WS_XL + i] = xl;
        ws[WS_SX + i] = sx;
        ws[WS_XXX + i] = xxx;
    }
}

// ---------------- k2a: split-K partials of xxx @ maa_w1 (4096x320) -------
__global__ __launch_bounds__(320)
void k2a_maa_down(const void* __restrict__ w1, float* __restrict__ ws) {
    bool isbf = ws[WS_FLAG] != 0.0f;
    __shared__ float lx[64];
    int tid = threadIdx.x, b = blockIdx.x;
    if (tid < 64) lx[tid] = ws[WS_XXX + b * 64 + tid];
    __syncthreads();
    float acc = 0.f;
    long long base = (long long)b * 64 * 320 + tid;
    #pragma unroll 8
    for (int j = 0; j < 64; ++j) acc += lx[j] * ldin(w1, base + (long long)j * 320, isbf);
    ws[WS_PART + b * 320 + tid] = acc;
}

// ---------------- k2c: z=tanh(.), LoRA up, mvals -------------------------
__global__ __launch_bounds__(256)
void k2c_maa_up(const void* __restrict__ w2, const void* __restrict__ tm,
                float* __restrict__ ws) {
    bool isbf = ws[WS_FLAG] != 0.0f;
    int tid = threadIdx.x;
    int f = blockIdx.x >> 4;
    int hb = (blockIdx.x & 15) << 8;
    __shared__ float zl[64];
    if (tid < 64) {
        float s = 0.f;
        #pragma unroll 8
        for (int b = 0; b < 64; ++b) s += ws[WS_PART + b * 320 + f * 64 + tid];
        zl[tid] = tanhf(s);
    }
    __syncthreads();
    int h = hb + tid;
    float acc = 0.f;
    long long base = (long long)f * 64 * HDIM + h;
    #pragma unroll 8
    for (int t = 0; t < 64; ++t) acc += zl[t] * ldin(w2, base + (long long)t * HDIM, isbf);
    float mval = ws[WS_XL + h] + ws[WS_SX + h] * (acc + ldin(tm, f * HDIM + h, isbf));
    ws[WS_MV + f * HDIM + h] = mval;
}

// ---------------- k3a: split-K partials of mw @ decay_w1 (4096x128) ------
__global__ __launch_bounds__(128)
void k3a_decay_down(const void* __restrict__ dw1, float* __restrict__ ws) {
    bool isbf = ws[WS_FLAG] != 0.0f;
    __shared__ float lm[32];
    int tid = threadIdx.x, b = blockIdx.x;
    if (tid < 32) lm[tid] = ws[WS_MV + b * 32 + tid];        // mw is f=0
    __syncthreads();
    float acc = 0.f;
    long long base = (long long)b * 32 * 128 + tid;
    #pragma unroll 8
    for (int j = 0; j < 32; ++j) acc += lm[j] * ldin(dw1, base + (long long)j * 128, isbf);
    ws[WS_DPART + b * 128 + tid] = acc;
}

// ---------------- k3b: dz=tanh(.), td = exp(-exp(clip(...))) -------------
__global__ __launch_bounds__(128)
void k3b_decay_up(const void* __restrict__ dw2, const void* __restrict__ tdec,
                  float* __restrict__ ws) {
    bool isbf = ws[WS_FLAG] != 0.0f;
    int tid = threadIdx.x;
    __shared__ float dz[128];
    {
        float s = 0.f;
        #pragma unroll 8
        for (int b = 0; b < 128; ++b) s += ws[WS_DPART + b * 128 + tid];
        dz[tid] = tanhf(s);
    }
    __syncthreads();
    int i = blockIdx.x * 128 + tid;
    float acc = 0.f;
    #pragma unroll 8
    for (int t = 0; t < 128; ++t) acc += dz[t] * ldin(dw2, (long long)t * HDIM + i, isbf);
    float tv = acc + ldin(tdec, i, isbf);
    tv = fminf(fmaxf(tv, -9.72f), 2.27f);
    ws[WS_TD + i] = expf(-expf(tv));
}

// ---------------- bf16 row helpers: issue 8 x 16B, consume vs LDS m ------
__device__ __forceinline__ void issue8(const bfraw* __restrict__ wr, int lane,
                                       uint4 buf[8]) {
    #pragma unroll
    for (int it = 0; it < 8; ++it)
        buf[it] = *(const uint4*)(wr + it * 512 + lane * 8);
}
__device__ __forceinline__ float consume8(const uint4 buf[8],
                                          const float* __restrict__ mLds, int lane) {
    float acc = 0.f;
    #pragma unroll
    for (int it = 0; it < 8; ++it) {
        int base = it * 512 + lane * 8;
        float4 m0 = *(const float4*)(mLds + base);
        float4 m1 = *(const float4*)(mLds + base + 4);
        uint4 w4 = buf[it];
        acc += bf2f((bfraw)(w4.x & 0xffff)) * m0.x + bf2f((bfraw)(w4.x >> 16)) * m0.y;
        acc += bf2f((bfraw)(w4.y & 0xffff)) * m0.z + bf2f((bfraw)(w4.y >> 16)) * m0.w;
        acc += bf2f((bfraw)(w4.z & 0xffff)) * m1.x + bf2f((bfraw)(w4.z >> 16)) * m1.y;
        acc += bf2f((bfraw)(w4.w & 0xffff)) * m1.z + bf2f((bfraw)(w4.w >> 16)) * m1.w;
    }
    return acc;
}
__device__ __forceinline__ float dot_row_f32(const float* __restrict__ wr,
                                             const float* __restrict__ mLds, int lane) {
    float acc = 0.f;
    #pragma unroll
    for (int h = 0; h < 2; ++h) {
        float4 av[8];
        #pragma unroll
        for (int it = 0; it < 8; ++it)
            av[it] = *(const float4*)(wr + h * 2048 + it * 256 + lane * 4);
        __builtin_amdgcn_sched_barrier(0);
        #pragma unroll
        for (int it = 0; it < 8; ++it) {
            int base = h * 2048 + it * 256 + lane * 4;
            float4 m0 = *(const float4*)(mLds + base);
            float4 a = av[it];
            acc += a.x * m0.x + a.y * m0.y + a.z * m0.z + a.w * m0.w;
        }
    }
    return acc;
}

// ---------------- k4: 4 big matvecs r,k,v,g ------------------------------
// 1024 blocks x 4 waves x 4 rows/wave. Register double-buffer: rows 0+1
// issued (16 loads in flight), then roll — in-flight never drains to 0.
__global__ __launch_bounds__(256)
void k4_matvec4(const void* __restrict__ Wr, const void* __restrict__ Wk,
                const void* __restrict__ Wv, const void* __restrict__ Wg,
                float* __restrict__ ws) {
    bool isbf = ws[WS_FLAG] != 0.0f;
    int tid = threadIdx.x;
    int wid = tid >> 6, lane = tid & 63;
    int mat = blockIdx.x >> 8;           // 256 blocks per matrix
    int bb = blockIdx.x & 255;
    const void* W; const float* msrc; float* y;
    if (mat == 0)      { W = Wr; msrc = ws + WS_MV + 3 * HDIM; y = ws + WS_R; }
    else if (mat == 1) { W = Wk; msrc = ws + WS_MV + 1 * HDIM; y = ws + WS_K; }
    else if (mat == 2) { W = Wv; msrc = ws + WS_MV + 2 * HDIM; y = ws + WS_V; }
    else               { W = Wg; msrc = ws + WS_MV + 4 * HDIM; y = ws + WS_G; }
    __shared__ __align__(16) float lm[HDIM];
    for (int i = tid * 4; i < HDIM; i += 1024)
        *(float4*)(lm + i) = *(const float4*)(msrc + i);
    __syncthreads();
    int r0 = bb * 16 + wid * 4;          // 4 contiguous rows per wave
    float acc0, acc1, acc2, acc3;
    if (isbf) {
        const bfraw* w0 = (const bfraw*)W + (long long)r0 * HDIM;
        uint4 A[8], B[8];
        issue8(w0, lane, A);
        issue8(w0 + HDIM, lane, B);
        __builtin_amdgcn_sched_barrier(0);
        acc0 = consume8(A, lm, lane);              // waits vmcnt(8), B in flight
        issue8(w0 + 2 * HDIM, lane, A);
        __builtin_amdgcn_sched_barrier(0);
        acc1 = consume8(B, lm, lane);
        issue8(w0 + 3 * HDIM, lane, B);
        __builtin_amdgcn_sched_barrier(0);
        acc2 = consume8(A, lm, lane);
        acc3 = consume8(B, lm, lane);
    } else {
        const float* w0 = (const float*)W + (long long)r0 * HDIM;
        acc0 = dot_row_f32(w0, lm, lane);
        acc1 = dot_row_f32(w0 + HDIM, lm, lane);
        acc2 = dot_row_f32(w0 + 2 * HDIM, lm, lane);
        acc3 = dot_row_f32(w0 + 3 * HDIM, lm, lane);
    }
    acc0 = waveReduce(acc0); acc1 = waveReduce(acc1);
    acc2 = waveReduce(acc2); acc3 = waveReduce(acc3);
    if (lane == 0) {
        if (mat == 3) {
            acc0 = acc0 / (1.0f + expf(-acc0));
            acc1 = acc1 / (1.0f + expf(-acc1));
            acc2 = acc2 / (1.0f + expf(-acc2));
            acc3 = acc3 / (1.0f + expf(-acc3));
        }
        y[r0] = acc0; y[r0 + 1] = acc1; y[r0 + 2] = acc2; y[r0 + 3] = acc3;
    }
}

// ---------------- k5: per-head state update + readout + IN + gate --------
__global__ __launch_bounds__(64)
void k5_heads(const void* __restrict__ state2, const void* __restrict__ tfirst,
              const void* __restrict__ lnxw, const void* __restrict__ lnxb,
              void* __restrict__ dout, float* __restrict__ ws) {
    bool isbf = ws[WS_FLAG] != 0.0f;
    int h = blockIdx.x, j = threadIdx.x;
    int gi = h * 64 + j;
    float rj = ws[WS_R + gi], kj = ws[WS_K + gi], vj = ws[WS_V + gi];
    float tdj = ws[WS_TD + gi];
    float tfj = ldin(tfirst, gi, isbf);
    __shared__ float lr[64], lk[64], ltd[64];
    lr[j] = rj; lk[j] = kj; ltd[j] = tdj;
    float c = waveReduce(rj * kj * tfj);   // sum_i r_i k_i tf_i
    __syncthreads();
    float acc = 0.f;
    long long sbase = (long long)h * 4096 + j;
    #pragma unroll 8
    for (int i = 0; i < 64; ++i) {
        float s = ldin(state2, sbase + i * 64, isbf);
        acc += lr[i] * s;                                            // r @ state2 part
        stout(dout, 8192 + sbase + i * 64, lk[i] * vj + s * ltd[i], isbf);  // output 2
    }
    float oh = vj * c + acc;                            // r @ (kv*tf + s)
    float s1 = waveReduce(oh);
    float s2 = waveReduce(oh * oh);
    float mu = s1 * (1.0f / 64.0f);
    float var = fmaxf(s2 * (1.0f / 64.0f) - mu * mu, 0.0f);
    float rstd = rsqrtf(var + 1e-5f);
    float o = (oh - mu) * rstd * ldin(lnxw, gi, isbf) + ldin(lnxb, gi, isbf);
    ws[WS_OG + gi] = o * ws[WS_G + gi];
}

// ---------------- k6: out0 = x + og @ Wo.T -------------------------------
// 512 blocks x 4 waves x 2 rows/wave, A/B pipelined.
__global__ __launch_bounds__(256)
void k6_out(const void* __restrict__ Wo, const void* __restrict__ x,
            void* __restrict__ dout, float* __restrict__ ws) {
    bool isbf = ws[WS_FLAG] != 0.0f;
    int tid = threadIdx.x;
    int wid = tid >> 6, lane = tid & 63;
    __shared__ __align__(16) float lm[HDIM];
    for (int i = tid * 4; i < HDIM; i += 1024)
        *(float4*)(lm + i) = *(const float4*)(ws + WS_OG + i);
    __syncthreads();
    int r0 = blockIdx.x * 8 + wid * 2;   // 2 contiguous rows per wave
    float acc0, acc1;
    if (isbf) {
        const bfraw* w0 = (const bfraw*)Wo + (long long)r0 * HDIM;
        uint4 A[8], B[8];
        issue8(w0, lane, A);
        issue8(w0 + HDIM, lane, B);
        __builtin_amdgcn_sched_barrier(0);
        acc0 = consume8(A, lm, lane);
        acc1 = consume8(B, lm, lane);
    } else {
        const float* w0 = (const float*)Wo + (long long)r0 * HDIM;
        acc0 = dot_row_f32(w0, lm, lane);
        acc1 = dot_row_f32(w0 + HDIM, lm, lane);
    }
    acc0 = waveReduce(acc0); acc1 = waveReduce(acc1);
    if (lane == 0) {
        stout(dout, r0,     ldin(x, r0, isbf)     + acc0, isbf);
        stout(dout, r0 + 1, ldin(x, r0 + 1, isbf) + acc1, isbf);
    }
}

extern "C" void kernel_launch(void* const* d_in, const int* in_sizes, int n_in,
                              void* d_out, int out_size, void* d_ws, size_t ws_size,
                              hipStream_t stream) {
    const void* x      = d_in[0];
    const void* st1    = d_in[1];
    const void* st2    = d_in[2];
    const void* ln1w   = d_in[3];
    const void* ln1b   = d_in[4];
    const void* tmx    = d_in[5];
    const void* tmaa   = d_in[6];
    const void* maw1   = d_in[7];
    const void* maw2   = d_in[8];
    const void* tdec   = d_in[9];
    const void* tfirst = d_in[10];
    const void* dw1    = d_in[11];
    const void* dw2    = d_in[12];
    const void* Wr     = d_in[13];
    const void* Wk     = d_in[14];
    const void* Wv     = d_in[15];
    const void* Wg     = d_in[16];
    const void* Wo     = d_in[17];
    const void* lnxw   = d_in[18];
    const void* lnxb   = d_in[19];

    float* ws = (float*)d_ws;

    k1_ln_mix<<<1, 256, 0, stream>>>(x, st1, ln1w, ln1b, tmx, d_out, ws);
    k2a_maa_down<<<64, 320, 0, stream>>>(maw1, ws);
    k2c_maa_up<<<80, 256, 0, stream>>>(maw2, tmaa, ws);
    k3a_decay_down<<<128, 128, 0, stream>>>(dw1, ws);
    k3b_decay_up<<<32, 128, 0, stream>>>(dw2, tdec, ws);
    k4_matvec4<<<1024, 256, 0, stream>>>(Wr, Wk, Wv, Wg, ws);
    k5_heads<<<64, 64, 0, stream>>>(st2, tfirst, lnxw, lnxb, d_out, ws);
    k6_out<<<512, 256, 0, stream>>>(Wo, x, d_out, ws);
}

// Round 4
// 392.177 us; speedup vs baseline: 1.0663x; 1.0663x over previous
//
#include <hip/hip_runtime.h>
#include <hip/hip_bf16.h>

// RWKV6 single-token self-attention, H=4096, NH=64, HS=64, TM=64, TD=128.
// R9: 5-kernel fused chain (no cooperative launch — R8's grid.sync killed
// the container). Dependency-graph re-derivation:
//  kA : LN recomputed per block (x is 16KB) + k2a split-K partials
//       (64 blocks; block 0 also writes dtype flag; xl -> output 1)
//  kB : k2c LoRA-up -> mvals (blocks 0-79)  PARALLEL WITH
//       k3a partials w/ mw recomputed from PART (blocks 80-207)
//  kC : k3b -> td (blocks 0-31)  PARALLEL WITH
//       k4 matvecs r,k,v,g (blocks 32-1055, R7 register-pipeline body)
//  kD : k5 heads (state update -> output 2, instance-norm, gate -> og)
//  kE : k6 out0 = x + og @ Wo.T (output 0)
// All compute bodies verbatim from R1/R2 proven-passing kernels.

#define HDIM 4096

// workspace layout (overlays only across kernel boundaries, never within)
#define WS_XL    0        // 4096   written kA, read kB
#define WS_SX    4096     // 4096   written kA, read kB
#define WS_MV    8192     // 20480  written kB, read kC          (ends 28672)
#define WS_PART  28672    // 20480  written kA, read kB          (ends 49152)
#define WS_R     28672    // 16384  written kC, read kD (overlays dead PART)
#define WS_TD    45056    // 4096   written kC, read kD
#define WS_DPART 49152    // 16384  written kB, read kC          (ends 65536)
#define WS_OG    65536    // 4096   written kD, read kE (overlays dead DPART)
#define WS_FLAG  69632    // 1      written kA, read kB..kE
// total 69633 floats ~= 272 KB of d_ws

typedef unsigned short bfraw;

__device__ __forceinline__ float bf2f(bfraw u) {
    union { unsigned int u; float f; } v; v.u = ((unsigned int)u) << 16; return v.f;
}
__device__ __forceinline__ bfraw f2bf(float f) {
    union { float f; unsigned int u; } v; v.f = f;
    unsigned int u = v.u;
    unsigned int r = (u + 0x7fffu + ((u >> 16) & 1u)) >> 16;  // RNE
    return (bfraw)r;
}
__device__ __forceinline__ float ldin(const void* p, long long i, bool isbf) {
    return isbf ? bf2f(((const bfraw*)p)[i]) : ((const float*)p)[i];
}
__device__ __forceinline__ void stout(void* p, long long i, float v, bool isbf) {
    if (isbf) ((bfraw*)p)[i] = f2bf(v); else ((float*)p)[i] = v;
}
__device__ __forceinline__ float waveReduce(float v) {
    for (int m = 32; m; m >>= 1) v += __shfl_xor(v, m);
    return v;
}

// issue 8x16B weight loads for one bf16 row (8KB, coalesced)
__device__ __forceinline__ void issue8(const bfraw* __restrict__ wr, int lane,
                                       uint4 buf[8]) {
    #pragma unroll
    for (int it = 0; it < 8; ++it)
        buf[it] = *(const uint4*)(wr + it * 512 + lane * 8);
}
// consume one row vs m staged in LDS (lgkmcnt path, keeps vmcnt clean)
__device__ __forceinline__ float consume8(const uint4 buf[8],
                                          const float* __restrict__ mLds, int lane) {
    float acc = 0.f;
    #pragma unroll
    for (int it = 0; it < 8; ++it) {
        int base = it * 512 + lane * 8;
        float4 m0 = *(const float4*)(mLds + base);
        float4 m1 = *(const float4*)(mLds + base + 4);
        uint4 w4 = buf[it];
        acc += bf2f((bfraw)(w4.x & 0xffff)) * m0.x + bf2f((bfraw)(w4.x >> 16)) * m0.y;
        acc += bf2f((bfraw)(w4.y & 0xffff)) * m0.z + bf2f((bfraw)(w4.y >> 16)) * m0.w;
        acc += bf2f((bfraw)(w4.z & 0xffff)) * m1.x + bf2f((bfraw)(w4.z >> 16)) * m1.y;
        acc += bf2f((bfraw)(w4.w & 0xffff)) * m1.z + bf2f((bfraw)(w4.w >> 16)) * m1.w;
    }
    return acc;
}
__device__ __forceinline__ float dot_row_f32(const float* __restrict__ wr,
                                             const float* __restrict__ mLds, int lane) {
    float acc = 0.f;
    #pragma unroll
    for (int h = 0; h < 2; ++h) {
        float4 av[8];
        #pragma unroll
        for (int it = 0; it < 8; ++it)
            av[it] = *(const float4*)(wr + h * 2048 + it * 256 + lane * 4);
        #pragma unroll
        for (int it = 0; it < 8; ++it) {
            int base = h * 2048 + it * 256 + lane * 4;
            float4 m0 = *(const float4*)(mLds + base);
            float4 a = av[it];
            acc += a.x * m0.x + a.y * m0.y + a.z * m0.z + a.w * m0.w;
        }
    }
    return acc;
}

// ---------------- kA: per-block LN recompute + k2a split-K ---------------
// 64 blocks x 256. Each block: dtype ballot, full-x LN stats (redundant,
// x is 16KB and L2-hot), write its own 64-wide slice of xl/sx (+dout),
// then its split-K partial dots vs maa_w1.
__global__ __launch_bounds__(256)
void kA_ln_k2a(const void* __restrict__ x, const void* __restrict__ st1,
               const void* __restrict__ lnw, const void* __restrict__ lnb,
               const void* __restrict__ tmx, const void* __restrict__ w1,
               void* __restrict__ dout, float* __restrict__ ws) {
    int tid = threadIdx.x, b = blockIdx.x;
    int wid = tid >> 6, lane = tid & 63;
    bool isbf;
    {
        bfraw u = ((const bfraw*)x)[lane];
        int e = (u >> 7) & 0xFF;
        unsigned long long ball = __ballot(e >= 96 && e <= 144);
        isbf = __popcll(ball) >= 56;     // bf16 N(0,1): ~64/64 sane exps
    }
    if (b == 0 && tid == 0) ws[WS_FLAG] = isbf ? 1.0f : 0.0f;

    __shared__ float red[8];
    __shared__ float lx[64];
    float xv[16]; float s1 = 0.f, s2 = 0.f;
    for (int k = 0; k < 16; ++k) {
        float v = ldin(x, tid + k * 256, isbf);
        xv[k] = v; s1 += v; s2 += v * v;
    }
    s1 = waveReduce(s1); s2 = waveReduce(s2);
    if (lane == 0) { red[wid] = s1; red[4 + wid] = s2; }
    __syncthreads();
    float t1 = red[0] + red[1] + red[2] + red[3];
    float t2 = red[4] + red[5] + red[6] + red[7];
    float mu = t1 * (1.0f / HDIM);
    float var = fmaxf(t2 * (1.0f / HDIM) - mu * mu, 0.0f);
    float rstd = rsqrtf(var + 1e-5f);
    for (int k = 0; k < 16; ++k) {
        int i = tid + k * 256;
        if ((i >> 6) == b) {             // this block's 64-wide slice only
            float xl = (xv[k] - mu) * rstd * ldin(lnw, i, isbf) + ldin(lnb, i, isbf);
            float sx = ldin(st1, i, isbf) - xl;
            float xxx = xl + sx * ldin(tmx, i, isbf);
            stout(dout, 4096 + i, xl, isbf);   // output 1: xl
            ws[WS_XL + i] = xl;
            ws[WS_SX + i] = sx;
            lx[i & 63] = xxx;
        }
    }
    __syncthreads();
    for (int c = tid; c < 320; c += 256) {
        float acc = 0.f;
        long long base = (long long)b * 64 * 320 + c;
        #pragma unroll 8
        for (int j = 0; j < 64; ++j)
            acc += lx[j] * ldin(w1, base + (long long)j * 320, isbf);
        ws[WS_PART + b * 320 + c] = acc;
    }
}

// ---------------- kB: k2c (blocks 0-79) || k3a w/ recomputed mw ----------
__global__ __launch_bounds__(256)
void kB_up_k3a(const void* __restrict__ w2, const void* __restrict__ tm,
               const void* __restrict__ dw1, float* __restrict__ ws) {
    bool isbf = ws[WS_FLAG] != 0.0f;
    int tid = threadIdx.x, b = blockIdx.x;
    __shared__ float zl[64];
    __shared__ float mwl[32];
    if (b < 80) {
        // ---- k2c: z=tanh(reduce PART), LoRA up -> mvals (R1 body) ----
        int f = b >> 4, hb = (b & 15) << 8;
        if (tid < 64) {
            float s = 0.f;
            #pragma unroll 8
            for (int p = 0; p < 64; ++p) s += ws[WS_PART + p * 320 + f * 64 + tid];
            zl[tid] = tanhf(s);
        }
        __syncthreads();
        int h = hb + tid;
        float acc = 0.f;
        long long base = (long long)f * 64 * HDIM + h;
        #pragma unroll 8
        for (int t = 0; t < 64; ++t)
            acc += zl[t] * ldin(w2, base + (long long)t * HDIM, isbf);
        float mval = ws[WS_XL + h] + ws[WS_SX + h] * (acc + ldin(tm, (long long)f * HDIM + h, isbf));
        ws[WS_MV + f * HDIM + h] = mval;
    } else {
        // ---- k3a: recompute mw slice from PART (f=0), then partials ----
        int d = b - 80;                  // 0..127, K-slice rows d*32..d*32+31
        if (tid < 64) {
            float s = 0.f;
            #pragma unroll 8
            for (int p = 0; p < 64; ++p) s += ws[WS_PART + p * 320 + tid];  // f=0
            zl[tid] = tanhf(s);
        }
        __syncthreads();
        if (tid < 32) {
            int h = d * 32 + tid;
            float acc = 0.f;
            #pragma unroll 8
            for (int t = 0; t < 64; ++t)
                acc += zl[t] * ldin(w2, (long long)t * HDIM + h, isbf);     // f=0
            mwl[tid] = ws[WS_XL + h] + ws[WS_SX + h] * (acc + ldin(tm, h, isbf));
        }
        __syncthreads();
        if (tid < 128) {
            float acc = 0.f;
            long long base = (long long)d * 32 * 128 + tid;
            #pragma unroll 8
            for (int j = 0; j < 32; ++j)
                acc += mwl[j] * ldin(dw1, base + (long long)j * 128, isbf);
            ws[WS_DPART + d * 128 + tid] = acc;
        }
    }
}

// ---------------- kC: k3b (blocks 0-31) || k4 matvecs (blocks 32-1055) ---
__global__ __launch_bounds__(256)
void kC_k3b_k4(const void* __restrict__ dw2, const void* __restrict__ tdec,
               const void* __restrict__ Wr, const void* __restrict__ Wk,
               const void* __restrict__ Wv, const void* __restrict__ Wg,
               float* __restrict__ ws) {
    bool isbf = ws[WS_FLAG] != 0.0f;
    int tid = threadIdx.x;
    __shared__ __align__(16) float lm[HDIM];
    if (blockIdx.x < 32) {
        // ---- k3b: dz=tanh(reduce DPART), td (R1 body; dz in lm[0:128]) --
        int bb = blockIdx.x;
        if (tid < 128) {
            float s = 0.f;
            #pragma unroll 8
            for (int p = 0; p < 128; ++p) s += ws[WS_DPART + p * 128 + tid];
            lm[tid] = tanhf(s);
        }
        __syncthreads();
        if (tid < 128) {
            int i = bb * 128 + tid;
            float acc = 0.f;
            #pragma unroll 8
            for (int t = 0; t < 128; ++t)
                acc += lm[t] * ldin(dw2, (long long)t * HDIM + i, isbf);
            float tv = acc + ldin(tdec, i, isbf);
            tv = fminf(fmaxf(tv, -9.72f), 2.27f);
            ws[WS_TD + i] = expf(-expf(tv));
        }
        return;
    }
    // ---- k4: R7 register-pipeline body, 4 rows/wave -------------------
    int k4b = blockIdx.x - 32;
    int wid = tid >> 6, lane = tid & 63;
    int mat = k4b >> 8;                  // 256 blocks per matrix
    int bb = k4b & 255;
    const void* W; const float* msrc;
    if (mat == 0)      { W = Wr; msrc = ws + WS_MV + 3 * HDIM; }
    else if (mat == 1) { W = Wk; msrc = ws + WS_MV + 1 * HDIM; }
    else if (mat == 2) { W = Wv; msrc = ws + WS_MV + 2 * HDIM; }
    else               { W = Wg; msrc = ws + WS_MV + 4 * HDIM; }
    float* y = ws + WS_R + mat * HDIM;
    for (int i = tid * 4; i < HDIM; i += 1024)
        *(float4*)(lm + i) = *(const float4*)(msrc + i);
    __syncthreads();
    int r0 = bb * 16 + wid * 4;          // 4 contiguous rows per wave
    float acc0, acc1, acc2, acc3;
    if (isbf) {
        const bfraw* w0 = (const bfraw*)W + (long long)r0 * HDIM;
        uint4 A[8], B[8];
        issue8(w0, lane, A);
        issue8(w0 + HDIM, lane, B);
        __builtin_amdgcn_sched_barrier(0);
        acc0 = consume8(A, lm, lane);
        issue8(w0 + 2 * HDIM, lane, A);
        __builtin_amdgcn_sched_barrier(0);
        acc1 = consume8(B, lm, lane);
        issue8(w0 + 3 * HDIM, lane, B);
        __builtin_amdgcn_sched_barrier(0);
        acc2 = consume8(A, lm, lane);
        acc3 = consume8(B, lm, lane);
    } else {
        const float* w0 = (const float*)W + (long long)r0 * HDIM;
        acc0 = dot_row_f32(w0, lm, lane);
        acc1 = dot_row_f32(w0 + HDIM, lm, lane);
        acc2 = dot_row_f32(w0 + 2 * HDIM, lm, lane);
        acc3 = dot_row_f32(w0 + 3 * HDIM, lm, lane);
    }
    acc0 = waveReduce(acc0); acc1 = waveReduce(acc1);
    acc2 = waveReduce(acc2); acc3 = waveReduce(acc3);
    if (lane == 0) {
        if (mat == 3) {
            acc0 = acc0 / (1.0f + expf(-acc0));
            acc1 = acc1 / (1.0f + expf(-acc1));
            acc2 = acc2 / (1.0f + expf(-acc2));
            acc3 = acc3 / (1.0f + expf(-acc3));
        }
        y[r0] = acc0; y[r0 + 1] = acc1; y[r0 + 2] = acc2; y[r0 + 3] = acc3;
    }
}

// ---------------- kD: k5 per-head state update + readout + IN + gate -----
__global__ __launch_bounds__(64)
void kD_heads(const void* __restrict__ state2, const void* __restrict__ tfirst,
              const void* __restrict__ lnxw, const void* __restrict__ lnxb,
              void* __restrict__ dout, float* __restrict__ ws) {
    bool isbf = ws[WS_FLAG] != 0.0f;
    int h = blockIdx.x, j = threadIdx.x;
    int gi = h * 64 + j;
    float rj = ws[WS_R + gi], kj = ws[WS_R + HDIM + gi];
    float vj = ws[WS_R + 2 * HDIM + gi], gj = ws[WS_R + 3 * HDIM + gi];
    float tdj = ws[WS_TD + gi];
    float tfj = ldin(tfirst, gi, isbf);
    __shared__ float lr[64], lk[64], ltd[64];
    lr[j] = rj; lk[j] = kj; ltd[j] = tdj;
    float c = waveReduce(rj * kj * tfj);   // sum_i r_i k_i tf_i
    __syncthreads();
    float acc = 0.f;
    long long sbase = (long long)h * 4096 + j;
    #pragma unroll 8
    for (int i = 0; i < 64; ++i) {
        float s = ldin(state2, sbase + i * 64, isbf);
        acc += lr[i] * s;                                            // r @ state2 part
        stout(dout, 8192 + sbase + i * 64, lk[i] * vj + s * ltd[i], isbf);  // output 2
    }
    float oh = vj * c + acc;                            // r @ (kv*tf + s)
    float s1 = waveReduce(oh);
    float s2 = waveReduce(oh * oh);
    float mu = s1 * (1.0f / 64.0f);
    float var = fmaxf(s2 * (1.0f / 64.0f) - mu * mu, 0.0f);
    float rstd = rsqrtf(var + 1e-5f);
    float o = (oh - mu) * rstd * ldin(lnxw, gi, isbf) + ldin(lnxb, gi, isbf);
    ws[WS_OG + gi] = o * gj;
}

// ---------------- kE: k6 out0 = x + og @ Wo.T ----------------------------
__global__ __launch_bounds__(256)
void kE_out(const void* __restrict__ Wo, const void* __restrict__ x,
            void* __restrict__ dout, float* __restrict__ ws) {
    bool isbf = ws[WS_FLAG] != 0.0f;
    int tid = threadIdx.x;
    int wid = tid >> 6, lane = tid & 63;
    __shared__ __align__(16) float lm[HDIM];
    for (int i = tid * 4; i < HDIM; i += 1024)
        *(float4*)(lm + i) = *(const float4*)(ws + WS_OG + i);
    __syncthreads();
    int r0 = blockIdx.x * 8 + wid * 2;   // 2 contiguous rows per wave
    float acc0, acc1;
    if (isbf) {
        const bfraw* w0 = (const bfraw*)Wo + (long long)r0 * HDIM;
        uint4 A[8], B[8];
        issue8(w0, lane, A);
        issue8(w0 + HDIM, lane, B);
        __builtin_amdgcn_sched_barrier(0);
        acc0 = consume8(A, lm, lane);
        acc1 = consume8(B, lm, lane);
    } else {
        const float* w0 = (const float*)Wo + (long long)r0 * HDIM;
        acc0 = dot_row_f32(w0, lm, lane);
        acc1 = dot_row_f32(w0 + HDIM, lm, lane);
    }
    acc0 = waveReduce(acc0); acc1 = waveReduce(acc1);
    if (lane == 0) {
        stout(dout, r0,     ldin(x, r0, isbf)     + acc0, isbf);
        stout(dout, r0 + 1, ldin(x, r0 + 1, isbf) + acc1, isbf);
    }
}

extern "C" void kernel_launch(void* const* d_in, const int* in_sizes, int n_in,
                              void* d_out, int out_size, void* d_ws, size_t ws_size,
                              hipStream_t stream) {
    const void* x      = d_in[0];
    const void* st1    = d_in[1];
    const void* st2    = d_in[2];
    const void* ln1w   = d_in[3];
    const void* ln1b   = d_in[4];
    const void* tmx    = d_in[5];
    const void* tmaa   = d_in[6];
    const void* maw1   = d_in[7];
    const void* maw2   = d_in[8];
    const void* tdec   = d_in[9];
    const void* tfirst = d_in[10];
    const void* dw1    = d_in[11];
    const void* dw2    = d_in[12];
    const void* Wr     = d_in[13];
    const void* Wk     = d_in[14];
    const void* Wv     = d_in[15];
    const void* Wg     = d_in[16];
    const void* Wo     = d_in[17];
    const void* lnxw   = d_in[18];
    const void* lnxb   = d_in[19];

    float* ws = (float*)d_ws;

    kA_ln_k2a<<<64, 256, 0, stream>>>(x, st1, ln1w, ln1b, tmx, maw1, d_out, ws);
    kB_up_k3a<<<208, 256, 0, stream>>>(maw2, tmaa, dw1, ws);
    kC_k3b_k4<<<1056, 256, 0, stream>>>(dw2, tdec, Wr, Wk, Wv, Wg, ws);
    kD_heads<<<64, 64, 0, stream>>>(st2, tfirst, lnxw, lnxb, d_out, ws);
    kE_out<<<512, 256, 0, stream>>>(Wo, x, d_out, ws);
}